// Round 1
// baseline (56.829 us; speedup 1.0000x reference)
//
#include <hip/hip_runtime.h>
#include <hip/hip_bf16.h>

// loss_separation: X[n, b*2+c] = keypoints[b, n, c], N=8192 rows, K=128 cols.
// loss = sum_{i != j} exp(-0.4 * ||X_i - X_j||)
// Pipeline:
//   1. prep:   build bf16 X [8192][128] (+ fp32 row norms from bf16 values)
//   2. pairs:  upper-tri 128x128 tiles, MFMA bf16 dot products, exp epilogue
//   3. reduce: sum per-tile partials -> d_out[0]

#define N_KP   8192
#define KDIM   128          // B*C = 64*2
#define NT     64           // number of 128-row tiles
#define NTILES (NT * (NT + 1) / 2)   // 2080 upper-tri tiles
#define COEF   (-0.4f)

typedef __attribute__((ext_vector_type(8))) short bf16x8;
typedef __attribute__((ext_vector_type(4))) float f32x4;

__device__ __forceinline__ unsigned short f2bf(float f) {
    // round-to-nearest-even bf16 (inputs are uniform [0,1), no NaN/Inf)
    unsigned int u = __builtin_bit_cast(unsigned int, f);
    unsigned int r = (u + 0x7FFFu + ((u >> 16) & 1u)) >> 16;
    return (unsigned short)r;
}

__device__ __forceinline__ float bf2f(unsigned short u) {
    unsigned int x = ((unsigned int)u) << 16;
    return __builtin_bit_cast(float, x);
}

// One wave per keypoint n: lane b (0..63) reads keypoints[b, n, 0:2],
// writes packed bf16 pair to Xbf[n][2b:2b+2] (coalesced 4B stores),
// and wave-reduces sum of squares (of the bf16-rounded values) -> sq[n].
__global__ __launch_bounds__(256) void prep_kernel(
        const float* __restrict__ in, unsigned short* __restrict__ Xbf,
        float* __restrict__ sq) {
    int gwid = (blockIdx.x * blockDim.x + threadIdx.x) >> 6;  // = n
    int lane = threadIdx.x & 63;                              // = b
    if (gwid >= N_KP) return;
    int n = gwid;
    const float2 v = *(const float2*)(in + (size_t)lane * (N_KP * 2) + n * 2);
    unsigned short h0 = f2bf(v.x);
    unsigned short h1 = f2bf(v.y);
    unsigned int packed = ((unsigned int)h1 << 16) | h0;
    *(unsigned int*)(Xbf + (size_t)n * KDIM + lane * 2) = packed;
    float f0 = bf2f(h0), f1 = bf2f(h1);
    float s = f0 * f0 + f1 * f1;
    #pragma unroll
    for (int m = 32; m; m >>= 1) s += __shfl_xor(s, m, 64);
    if (lane == 0) sq[n] = s;
}

// Upper-triangular tile kernel. Block = 256 threads = 4 waves in a 2x2 grid;
// each wave computes a 64x64 output subtile via 4x4 fragments of
// mfma_f32_16x16x32_bf16 over K=128 (4 K-steps). Fragments are loaded
// directly from global (X is 2 MB -> L2 resident). Epilogue folds
// d2 = sq_i + sq_j - 2*dot -> exp(COEF*sqrt(d2)) and reduces to one
// partial per block.
__global__ __launch_bounds__(256) void pair_kernel(
        const unsigned short* __restrict__ Xbf, const float* __restrict__ sq,
        float* __restrict__ partials) {
    int bid = blockIdx.x;
    // decode (ti, tj), ti <= tj, from linear upper-tri index.
    // off(t) = t*(129-t)/2 tiles precede row t.
    int ti = (int)((129.0f - sqrtf(129.0f * 129.0f - 8.0f * (float)bid)) * 0.5f);
    while (ti > 0 && ti * (129 - ti) / 2 > bid) --ti;
    while ((ti + 1) * (129 - (ti + 1)) / 2 <= bid) ++ti;
    int tj = ti + (bid - ti * (129 - ti) / 2);

    int wid  = threadIdx.x >> 6;
    int lane = threadIdx.x & 63;
    int wr = wid >> 1, wc = wid & 1;
    int l16 = lane & 15, lhi = lane >> 4;

    int ibase = ti * 128 + wr * 64;
    int jbase = tj * 128 + wc * 64;

    f32x4 acc[4][4] = {};
    const unsigned short* Arow = Xbf + (size_t)(ibase + l16) * KDIM;
    const unsigned short* Brow = Xbf + (size_t)(jbase + l16) * KDIM;

    #pragma unroll
    for (int kk = 0; kk < 4; ++kk) {
        int koff = kk * 32 + lhi * 8;
        bf16x8 a[4], b[4];
        #pragma unroll
        for (int m = 0; m < 4; ++m)
            a[m] = *(const bf16x8*)(Arow + (size_t)m * 16 * KDIM + koff);
        #pragma unroll
        for (int n = 0; n < 4; ++n)
            b[n] = *(const bf16x8*)(Brow + (size_t)n * 16 * KDIM + koff);
        #pragma unroll
        for (int m = 0; m < 4; ++m)
            #pragma unroll
            for (int n = 0; n < 4; ++n)
                acc[m][n] = __builtin_amdgcn_mfma_f32_16x16x32_bf16(
                    a[m], b[n], acc[m][n], 0, 0, 0);
    }

    // epilogue: D[row][col], row = (lane>>4)*4 + r, col = lane&15 per fragment
    float sqj[4];
    #pragma unroll
    for (int n = 0; n < 4; ++n) sqj[n] = sq[jbase + n * 16 + l16];

    float partial = 0.0f;
    #pragma unroll
    for (int m = 0; m < 4; ++m) {
        #pragma unroll
        for (int r = 0; r < 4; ++r) {
            int i = ibase + m * 16 + lhi * 4 + r;
            float si = sq[i];
            #pragma unroll
            for (int n = 0; n < 4; ++n) {
                int j = jbase + n * 16 + l16;
                float d2 = si + sqj[n] - 2.0f * acc[m][n][r];
                float d = sqrtf(fmaxf(d2, 0.0f));
                float t = __expf(COEF * d);
                partial += (i == j) ? 0.0f : t;
            }
        }
    }
    if (ti != tj) partial *= 2.0f;   // mirror tile (tj, ti) not computed

    #pragma unroll
    for (int m = 32; m; m >>= 1) partial += __shfl_xor(partial, m, 64);
    __shared__ float wsum[4];
    if (lane == 0) wsum[wid] = partial;
    __syncthreads();
    if (threadIdx.x == 0)
        partials[bid] = (wsum[0] + wsum[1]) + (wsum[2] + wsum[3]);
}

__global__ __launch_bounds__(256) void reduce_kernel(
        const float* __restrict__ partials, float* __restrict__ out) {
    float s = 0.0f;
    for (int i = threadIdx.x; i < NTILES; i += 256) s += partials[i];
    #pragma unroll
    for (int m = 32; m; m >>= 1) s += __shfl_xor(s, m, 64);
    __shared__ float wsum[4];
    int wid = threadIdx.x >> 6, lane = threadIdx.x & 63;
    if (lane == 0) wsum[wid] = s;
    __syncthreads();
    if (threadIdx.x == 0) out[0] = (wsum[0] + wsum[1]) + (wsum[2] + wsum[3]);
}

extern "C" void kernel_launch(void* const* d_in, const int* in_sizes, int n_in,
                              void* d_out, int out_size, void* d_ws, size_t ws_size,
                              hipStream_t stream) {
    const float* in = (const float*)d_in[0];
    float* out = (float*)d_out;

    // workspace layout: Xbf (2 MB) | sq (32 KB) | partials (NTILES*4 B)
    unsigned short* Xbf = (unsigned short*)d_ws;
    float* sq = (float*)((char*)d_ws + (size_t)N_KP * KDIM * 2);
    float* partials = (float*)((char*)d_ws + (size_t)N_KP * KDIM * 2
                               + (size_t)N_KP * 4);

    prep_kernel<<<N_KP / 4, 256, 0, stream>>>(in, Xbf, sq);
    pair_kernel<<<NTILES, 256, 0, stream>>>(Xbf, sq, partials);
    reduce_kernel<<<1, 256, 0, stream>>>(partials, out);
}

// Round 2
// 45.529 us; speedup vs baseline: 1.2482x; 1.2482x over previous
//
#include <hip/hip_runtime.h>
#include <hip/hip_bf16.h>

// loss_separation: X[n, b*2+c] = keypoints[b, n, c], N=8192 rows, K=128 cols.
// loss = sum_{i != j} exp(-0.4 * ||X_i - X_j||)
// Pipeline:
//   1. prep:   build bf16 X in MFMA-fragment-swizzled layout + fp32 row norms
//   2. pairs:  upper-tri 128x128 tiles, MFMA bf16 dot products, exp epilogue
//   3. reduce: sum per-tile partials -> d_out[0]

#define N_KP   8192
#define KDIM   128          // B*C = 64*2
#define NT     64           // number of 128-row tiles
#define NTILES (NT * (NT + 1) / 2)   // 2080 upper-tri tiles
#define COEF   (-0.4f)

typedef __attribute__((ext_vector_type(8))) short bf16x8;
typedef __attribute__((ext_vector_type(4))) float f32x4;

// Swizzled X layout (ushort units): fragment f = (rowblk16*4 + kk) holds the
// MFMA A/B fragment for rows [rowblk16*16, +16), k in [kk*32, +32):
//   Xs[f*64 + lane][e]  =  X[rowblk16*16 + (lane&15)][kk*32 + (lane>>4)*8 + e]
// so a wave's fragment load is one contiguous 1 KB global_load_dwordx4.

__device__ __forceinline__ unsigned short f2bf(float f) {
    // round-to-nearest-even bf16 (inputs are uniform [0,1), no NaN/Inf)
    unsigned int u = __builtin_bit_cast(unsigned int, f);
    unsigned int r = (u + 0x7FFFu + ((u >> 16) & 1u)) >> 16;
    return (unsigned short)r;
}

__device__ __forceinline__ float bf2f(unsigned short u) {
    unsigned int x = ((unsigned int)u) << 16;
    return __builtin_bit_cast(float, x);
}

// One thread per keypoint n; loop over batch b. Reads are fully coalesced
// (64 lanes x float2 contiguous). Writes scatter 4B into the swizzled layout
// (L2 absorbs). sq[n] accumulated in-thread, no cross-lane needed.
__global__ __launch_bounds__(256) void prep_kernel(
        const float* __restrict__ in, unsigned short* __restrict__ Xbf,
        float* __restrict__ sq) {
    int n = blockIdx.x * 256 + threadIdx.x;
    int t16 = n >> 4, l16 = n & 15;
    unsigned int* dst = (unsigned int*)Xbf;
    float s = 0.0f;
    #pragma unroll 8
    for (int b = 0; b < 64; ++b) {
        float2 v = *(const float2*)(in + (size_t)b * (N_KP * 2) + n * 2);
        unsigned short h0 = f2bf(v.x);
        unsigned short h1 = f2bf(v.y);
        float f0 = bf2f(h0), f1 = bf2f(h1);
        s = fmaf(f0, f0, s);
        s = fmaf(f1, f1, s);
        // k = 2b (+c): kk = b>>4, lhi = (b>>2)&3, e = (b&3)*2
        unsigned int off_us = (((unsigned)(t16 * 4 + (b >> 4)) * 64
                                + ((b >> 2) & 3) * 16 + l16) << 3) + ((b & 3) << 1);
        dst[off_us >> 1] = ((unsigned int)h1 << 16) | h0;
    }
    sq[n] = s;
}

// Upper-triangular tile kernel. Block = 256 threads = 4 waves in a 2x2 grid;
// each wave computes a 64x64 output subtile via 4x4 fragments of
// mfma_f32_16x16x32_bf16 over K=128 (4 K-steps). Fragments load as single
// coalesced 1KB instructions from the swizzled layout (X is 2MB, L2-resident).
__global__ __launch_bounds__(256) void pair_kernel(
        const unsigned short* __restrict__ Xbf, const float* __restrict__ sq,
        float* __restrict__ partials) {
    int bid = blockIdx.x;
    // decode (ti, tj), ti <= tj: off(t) = t*(129-t)/2 tiles precede row t.
    int ti = (int)((129.0f - sqrtf(129.0f * 129.0f - 8.0f * (float)bid)) * 0.5f);
    while (ti > 0 && ti * (129 - ti) / 2 > bid) --ti;
    while ((ti + 1) * (129 - (ti + 1)) / 2 <= bid) ++ti;
    int tj = ti + (bid - ti * (129 - ti) / 2);

    int wid  = threadIdx.x >> 6;
    int lane = threadIdx.x & 63;
    int wr = wid >> 1, wc = wid & 1;
    int l16 = lane & 15, lhi = lane >> 4;

    int ibase = ti * 128 + wr * 64;   // rowblk16 = ti*8 + wr*4
    int jbase = tj * 128 + wc * 64;

    const bf16x8* Xs = (const bf16x8*)Xbf;   // one bf16x8 = 16B per lane-slot
    int afrag0 = (ti * 8 + wr * 4) * 4;      // fragment index base (x4 per kk)
    int bfrag0 = (tj * 8 + wc * 4) * 4;

    f32x4 acc[4][4] = {};
    #pragma unroll
    for (int kk = 0; kk < 4; ++kk) {
        bf16x8 a[4], b[4];
        #pragma unroll
        for (int m = 0; m < 4; ++m)
            a[m] = Xs[(size_t)(afrag0 + m * 4 + kk) * 64 + lane];
        #pragma unroll
        for (int n = 0; n < 4; ++n)
            b[n] = Xs[(size_t)(bfrag0 + n * 4 + kk) * 64 + lane];
        #pragma unroll
        for (int m = 0; m < 4; ++m)
            #pragma unroll
            for (int n = 0; n < 4; ++n)
                acc[m][n] = __builtin_amdgcn_mfma_f32_16x16x32_bf16(
                    a[m], b[n], acc[m][n], 0, 0, 0);
    }

    // epilogue: D[row][col], row = lhi*4 + r (+m*16), col = l16 (+n*16)
    float si[4][4];
    #pragma unroll
    for (int m = 0; m < 4; ++m)
        #pragma unroll
        for (int r = 0; r < 4; ++r)
            si[m][r] = sq[ibase + m * 16 + lhi * 4 + r];
    float sqj[4];
    #pragma unroll
    for (int n = 0; n < 4; ++n) sqj[n] = sq[jbase + n * 16 + l16];

    float p[4] = {0.0f, 0.0f, 0.0f, 0.0f};
    #pragma unroll
    for (int m = 0; m < 4; ++m) {
        #pragma unroll
        for (int n = 0; n < 4; ++n) {
            #pragma unroll
            for (int r = 0; r < 4; ++r) {
                float d2 = fmaf(-2.0f, acc[m][n][r], si[m][r] + sqj[n]);
                float d = sqrtf(fabsf(d2));       // abs: free input modifier
                p[r] += __expf(COEF * d);
            }
        }
    }
    float partial = (p[0] + p[1]) + (p[2] + p[3]);

    #pragma unroll
    for (int m = 32; m; m >>= 1) partial += __shfl_xor(partial, m, 64);
    __shared__ float wsum[4];
    if (lane == 0) wsum[wid] = partial;
    __syncthreads();
    if (threadIdx.x == 0) {
        float v = (wsum[0] + wsum[1]) + (wsum[2] + wsum[3]);
        // diagonal tiles: remove the 128 i==j terms (each ~= exp(0) = 1).
        // off-diagonal tiles: mirror tile (tj, ti) not computed -> double.
        if (ti == tj) v -= 128.0f; else v *= 2.0f;
        partials[bid] = v;
    }
}

__global__ __launch_bounds__(256) void reduce_kernel(
        const float* __restrict__ partials, float* __restrict__ out) {
    float s = 0.0f;
    for (int i = threadIdx.x; i < NTILES; i += 256) s += partials[i];
    #pragma unroll
    for (int m = 32; m; m >>= 1) s += __shfl_xor(s, m, 64);
    __shared__ float wsum[4];
    int wid = threadIdx.x >> 6, lane = threadIdx.x & 63;
    if (lane == 0) wsum[wid] = s;
    __syncthreads();
    if (threadIdx.x == 0) out[0] = (wsum[0] + wsum[1]) + (wsum[2] + wsum[3]);
}

extern "C" void kernel_launch(void* const* d_in, const int* in_sizes, int n_in,
                              void* d_out, int out_size, void* d_ws, size_t ws_size,
                              hipStream_t stream) {
    const float* in = (const float*)d_in[0];
    float* out = (float*)d_out;

    // workspace layout: Xs (2 MB) | sq (32 KB) | partials (NTILES*4 B)
    unsigned short* Xbf = (unsigned short*)d_ws;
    float* sq = (float*)((char*)d_ws + (size_t)N_KP * KDIM * 2);
    float* partials = (float*)((char*)d_ws + (size_t)N_KP * KDIM * 2
                               + (size_t)N_KP * 4);

    prep_kernel<<<N_KP / 256, 256, 0, stream>>>(in, Xbf, sq);
    pair_kernel<<<NTILES, 256, 0, stream>>>(Xbf, sq, partials);
    reduce_kernel<<<1, 256, 0, stream>>>(partials, out);
}